// Round 2
// baseline (48.037 us; speedup 1.0000x reference)
//
#include <hip/hip_runtime.h>
#include <hip/hip_bf16.h>

// Bundle-adjustment residual, 4 observations per thread.
//   p = poses[poses_idx]                              (7 floats: t[3], q[4])
//   pts = [patch_coords[patch_idx], elev[patch_idx]]  (3 floats)
//   rotated = quat_rotate(normalize(q), pts) + t
//   proj = cart2polar(rotated)                        (r, az, el)
//   out  = (proj - target) * weight
// Streaming inputs/outputs vectorized 16B/lane; gathers are cached scalar.

__global__ __launch_bounds__(256) void ba_residual_kernel(
    const float* __restrict__ poses,         // [4096,7]
    const float* __restrict__ patch_coords,  // [262144,2]
    const float* __restrict__ elev,          // [262144,1]
    const int*   __restrict__ poses_idx,     // [NOBS]
    const int*   __restrict__ patch_idx,     // [NOBS]
    const float* __restrict__ target,        // [NOBS,3]
    const float* __restrict__ weights,       // [NOBS,1]
    float*       __restrict__ out,           // [NOBS,3]
    int n4)                                  // NOBS/4
{
    int i4 = blockIdx.x * blockDim.x + threadIdx.x;
    if (i4 >= n4) return;

    // Vectorized streaming loads: 4 obs per thread.
    int4   pidx = reinterpret_cast<const int4*>(poses_idx)[i4];
    int4   qidx = reinterpret_cast<const int4*>(patch_idx)[i4];
    float4 w4   = reinterpret_cast<const float4*>(weights)[i4];
    float4 t0   = reinterpret_cast<const float4*>(target)[i4 * 3 + 0];
    float4 t1   = reinterpret_cast<const float4*>(target)[i4 * 3 + 1];
    float4 t2   = reinterpret_cast<const float4*>(target)[i4 * 3 + 2];

    int   pi[4] = {pidx.x, pidx.y, pidx.z, pidx.w};
    int   qi[4] = {qidx.x, qidx.y, qidx.z, qidx.w};
    float ww[4] = {w4.x, w4.y, w4.z, w4.w};
    float tg[12] = {t0.x, t0.y, t0.z, t0.w,
                    t1.x, t1.y, t1.z, t1.w,
                    t2.x, t2.y, t2.z, t2.w};

    float res[12];

#pragma unroll
    for (int k = 0; k < 4; ++k) {
        // Pose gather (4096*28B = 114 KB, L1/L2-cached)
        const float* p = poses + (size_t)pi[k] * 7;
        float tx = p[0], ty = p[1], tz = p[2];
        float qx = p[3], qy = p[4], qz = p[5], qw = p[6];
        float inv = rsqrtf(qx*qx + qy*qy + qz*qz + qw*qw);
        qx *= inv; qy *= inv; qz *= inv; qw *= inv;

        // Patch gather (3 MB, L2-resident)
        float2 pc = *reinterpret_cast<const float2*>(patch_coords + (size_t)qi[k] * 2);
        float px = pc.x, py = pc.y, pz = elev[qi[k]];

        // uv = cross(qv, pts)
        float ux = qy*pz - qz*py;
        float uy = qz*px - qx*pz;
        float uz = qx*py - qy*px;
        // cross(qv, uv)
        float cx = qy*uz - qz*uy;
        float cy = qz*ux - qx*uz;
        float cz = qx*uy - qy*ux;
        // rotated = pts + 2*(qw*uv + cross(qv,uv)) + t
        float rx = px + 2.0f*(qw*ux + cx) + tx;
        float ry = py + 2.0f*(qw*uy + cy) + ty;
        float rz = pz + 2.0f*(qw*uz + cz) + tz;

        // cart2polar (matches reference: r = sqrt(rho^2 + z^2))
        float rho = sqrtf(rx*rx + ry*ry);
        float r   = sqrtf(rho*rho + rz*rz);
        float az  = atan2f(ry, rx);
        float el  = atan2f(rz, rho);

        res[k*3 + 0] = (r  - tg[k*3 + 0]) * ww[k];
        res[k*3 + 1] = (az - tg[k*3 + 1]) * ww[k];
        res[k*3 + 2] = (el - tg[k*3 + 2]) * ww[k];
    }

    float4* o = reinterpret_cast<float4*>(out);
    o[i4 * 3 + 0] = make_float4(res[0], res[1], res[2],  res[3]);
    o[i4 * 3 + 1] = make_float4(res[4], res[5], res[6],  res[7]);
    o[i4 * 3 + 2] = make_float4(res[8], res[9], res[10], res[11]);
}

extern "C" void kernel_launch(void* const* d_in, const int* in_sizes, int n_in,
                              void* d_out, int out_size, void* d_ws, size_t ws_size,
                              hipStream_t stream) {
    const float* poses        = (const float*)d_in[0];
    const float* patch_coords = (const float*)d_in[1];
    const float* elev         = (const float*)d_in[2];
    const int*   poses_idx    = (const int*)d_in[3];
    const int*   patch_idx    = (const int*)d_in[4];
    const float* target       = (const float*)d_in[5];
    const float* weights      = (const float*)d_in[6];
    float*       out          = (float*)d_out;

    int n  = in_sizes[3];       // NUM_OBS (2097152, divisible by 4)
    int n4 = n / 4;
    int block = 256;
    int grid = (n4 + block - 1) / block;
    ba_residual_kernel<<<grid, block, 0, stream>>>(
        poses, patch_coords, elev, poses_idx, patch_idx, target, weights, out, n4);
}